// Round 1
// baseline (770.822 us; speedup 1.0000x reference)
//
#include <hip/hip_runtime.h>
#include <hip/hip_bf16.h>

#define N_ROI 262144
#define FDIM  256
#define HDIM  64
#define NNET  128

// monotonic float -> uint key (order-preserving), for atomicMax-based segment max
__device__ __forceinline__ unsigned fkey(float f) {
  unsigned u = __float_as_uint(f);
  return (u & 0x80000000u) ? ~u : (u | 0x80000000u);
}
__device__ __forceinline__ float fkey_inv(unsigned k) {
  unsigned u = (k & 0x80000000u) ? (k ^ 0x80000000u) : ~k;
  return __uint_as_float(u);
}

// -------- Kernel 1: per-ROI MLP score + per-block segment max --------------
// 256 ROIs per block. k-tiled GEMM: xT tile (transposed) + W1 tile in LDS,
// 8 ROI x 8 hidden register tile per thread. Fused ReLU + dot(W2) epilogue,
// reduced across the 8 hidden-groups with shfl_xor.
__global__ __launch_bounds__(256) void scores_kernel(
    const float* __restrict__ x, const int* __restrict__ group,
    const float* __restrict__ W1, const float* __restrict__ b1,
    const float* __restrict__ W2,
    float* __restrict__ score, unsigned* __restrict__ segmax)
{
  __shared__ float xT[16][256];   // [k within tile][roi row] 16 KiB
  __shared__ float w1t[16][64];   // [k within tile][hidden]   4 KiB
  __shared__ unsigned smax[NNET];

  const int tid = threadIdx.x;
  if (tid < NNET) smax[tid] = 0u;
  const int rg = tid >> 3;   // 0..31 : roi group (8 rois each)
  const int hg = tid & 7;    // 0..7  : hidden group (8 hiddens each)
  const long roiBase = (long)blockIdx.x * 256;

  float b1v[8], w2v[8];
#pragma unroll
  for (int j = 0; j < 8; ++j) { b1v[j] = b1[hg * 8 + j]; w2v[j] = W2[hg * 8 + j]; }

  float acc[8][8];
#pragma unroll
  for (int i = 0; i < 8; ++i)
#pragma unroll
    for (int j = 0; j < 8; ++j) acc[i][j] = 0.f;

  const float* xrow = x + (roiBase + tid) * FDIM;
  const int wk = tid >> 4;          // 0..15 k-row of W1 tile this thread stages
  const int wc = (tid & 15) * 4;    // 0..60 column

  // prefetch tile 0
  float4 vx0 = *(const float4*)(xrow + 0);
  float4 vx1 = *(const float4*)(xrow + 4);
  float4 vx2 = *(const float4*)(xrow + 8);
  float4 vx3 = *(const float4*)(xrow + 12);
  float4 vw  = *(const float4*)(W1 + wk * HDIM + wc);

  for (int t = 0; t < 16; ++t) {
    __syncthreads();   // previous tile's reads done
    xT[0][tid] = vx0.x;  xT[1][tid] = vx0.y;  xT[2][tid] = vx0.z;  xT[3][tid] = vx0.w;
    xT[4][tid] = vx1.x;  xT[5][tid] = vx1.y;  xT[6][tid] = vx1.z;  xT[7][tid] = vx1.w;
    xT[8][tid] = vx2.x;  xT[9][tid] = vx2.y;  xT[10][tid] = vx2.z; xT[11][tid] = vx2.w;
    xT[12][tid] = vx3.x; xT[13][tid] = vx3.y; xT[14][tid] = vx3.z; xT[15][tid] = vx3.w;
    *(float4*)&w1t[wk][wc] = vw;
    __syncthreads();
    if (t < 15) {   // prefetch next tile while computing this one
      const float* p = xrow + (t + 1) * 16;
      vx0 = *(const float4*)(p + 0);
      vx1 = *(const float4*)(p + 4);
      vx2 = *(const float4*)(p + 8);
      vx3 = *(const float4*)(p + 12);
      vw  = *(const float4*)(W1 + ((t + 1) * 16 + wk) * HDIM + wc);
    }
#pragma unroll
    for (int kk = 0; kk < 16; ++kk) {
      float a[8], b[8];
      *(float4*)&a[0] = *(const float4*)&xT[kk][rg * 8 + 0];
      *(float4*)&a[4] = *(const float4*)&xT[kk][rg * 8 + 4];
      *(float4*)&b[0] = *(const float4*)&w1t[kk][hg * 8 + 0];
      *(float4*)&b[4] = *(const float4*)&w1t[kk][hg * 8 + 4];
#pragma unroll
      for (int i = 0; i < 8; ++i)
#pragma unroll
        for (int j = 0; j < 8; ++j)
          acc[i][j] = fmaf(a[i], b[j], acc[i][j]);
    }
  }

  // epilogue: relu + second layer (b2 omitted: cancels in segment softmax)
  float s[8];
#pragma unroll
  for (int i = 0; i < 8; ++i) {
    float v = 0.f;
#pragma unroll
    for (int j = 0; j < 8; ++j)
      v += fmaxf(acc[i][j] + b1v[j], 0.f) * w2v[j];
    s[i] = v;
  }
#pragma unroll
  for (int off = 1; off < 8; off <<= 1)
#pragma unroll
    for (int i = 0; i < 8; ++i) s[i] += __shfl_xor(s[i], off, 64);

  if (hg == 0) {
    const long r0 = roiBase + rg * 8;
#pragma unroll
    for (int i = 0; i < 8; ++i) score[r0 + i] = s[i];
#pragma unroll
    for (int i = 0; i < 8; ++i) {
      int g = group[r0 + i];
      atomicMax(&smax[g], fkey(s[i]));
    }
  }
  __syncthreads();
  if (tid < NNET) { unsigned k = smax[tid]; if (k) atomicMax(&segmax[tid], k); }
}

// -------- Kernel 2: weighted segment accumulation --------------------------
// Each block owns (roi chunk of 1024, group half of 64). LDS partial num/denom
// for its 64 groups (64 KiB), wave-per-ROI, lane-strided dims (conflict-free
// ds_add_f32). Partials merged into global accumulators with atomicAdd.
__global__ __launch_bounds__(512) void accum_kernel(
    const float* __restrict__ x, const int* __restrict__ group,
    const float* __restrict__ score, const unsigned* __restrict__ segmax,
    float* __restrict__ num_g, float* __restrict__ denom_g)
{
  __shared__ float lnum[64][256];   // 64 KiB
  __shared__ float ldenom[64];
  __shared__ float lmax[NNET];

  const int tid = threadIdx.x;
  for (int i = tid; i < 64 * 256; i += 512) ((float*)lnum)[i] = 0.f;
  if (tid < 64) ldenom[tid] = 0.f;
  if (tid < NNET) lmax[tid] = fkey_inv(segmax[tid]);
  __syncthreads();

  const int half  = blockIdx.x & 1;
  const long base = (long)(blockIdx.x >> 1) * 1024;
  const int wave = tid >> 6, lane = tid & 63;
  const long i0 = base + (long)wave * 128;   // this wave's 128 ROIs

  // preload this wave's 128 group ids / scores into lanes, broadcast via shfl
  const int   g0 = group[i0 + lane],      g1 = group[i0 + 64 + lane];
  const float s0 = score[i0 + lane];
  const float s1 = score[i0 + 64 + lane];

  for (int r = 0; r < 128; ++r) {
    const int g = __shfl((r < 64) ? g0 : g1, r & 63, 64);
    if ((g >> 6) != half) continue;          // wave-uniform skip
    const float sc = __shfl((r < 64) ? s0 : s1, r & 63, 64);
    const float w = expf(sc - lmax[g]);
    const int gl = g & 63;
    const long xoff = (i0 + r) * (long)FDIM;
#pragma unroll
    for (int c = 0; c < 4; ++c) {            // lane-strided: dims lane, 64+lane, ...
      float xv = x[xoff + c * 64 + lane];
      atomicAdd(&lnum[gl][c * 64 + lane], w * xv);
    }
    if (lane == 0) atomicAdd(&ldenom[gl], w);
  }
  __syncthreads();

  for (int idx = tid; idx < 64 * 256; idx += 512) {
    float v = ((const float*)lnum)[idx];
    if (v != 0.f) atomicAdd(&num_g[half * 64 * 256 + idx], v);
  }
  if (tid < 64) {
    float v = ldenom[tid];
    if (v != 0.f) atomicAdd(&denom_g[half * 64 + tid], v);
  }
}

// -------- Kernel 3: normalize -----------------------------------------------
__global__ __launch_bounds__(256) void finalize_kernel(
    const float* __restrict__ num_g, const float* __restrict__ denom_g,
    float* __restrict__ out)
{
  const int idx = blockIdx.x * 256 + threadIdx.x;   // 32768
  const int g = idx >> 8;
  const float den = denom_g[g];
  out[idx] = (den > 0.f) ? num_g[idx] / fmaxf(den, 1e-30f) : 0.f;
}

extern "C" void kernel_launch(void* const* d_in, const int* in_sizes, int n_in,
                              void* d_out, int out_size, void* d_ws, size_t ws_size,
                              hipStream_t stream)
{
  const float* x     = (const float*)d_in[0];
  const int*   group = (const int*)d_in[1];
  const float* W1    = (const float*)d_in[2];
  const float* b1    = (const float*)d_in[3];
  const float* W2    = (const float*)d_in[4];
  // d_in[5] = b2: mathematically cancels in exp(score-max)/sum -> unused
  float* out = (float*)d_out;

  // workspace layout
  float*    score_ws  = (float*)d_ws;                       // N_ROI floats
  unsigned* segmax_ws = (unsigned*)(score_ws + N_ROI);      // NNET keys
  float*    num_ws    = (float*)(segmax_ws + NNET);         // NNET*FDIM
  float*    denom_ws  = num_ws + NNET * FDIM;               // NNET

  // zero the accumulator region (harness poisons ws with 0xAA every call)
  hipMemsetAsync(segmax_ws, 0, (size_t)(NNET + NNET * FDIM + NNET) * sizeof(float), stream);

  scores_kernel<<<N_ROI / 256, 256, 0, stream>>>(x, group, W1, b1, W2, score_ws, segmax_ws);
  accum_kernel<<<512, 512, 0, stream>>>(x, group, score_ws, segmax_ws, num_ws, denom_ws);
  finalize_kernel<<<NNET * FDIM / 256, 256, 0, stream>>>(num_ws, denom_ws, out);

  (void)in_sizes; (void)n_in; (void)out_size; (void)ws_size;
}

// Round 2
// 761.928 us; speedup vs baseline: 1.0117x; 1.0117x over previous
//
#include <hip/hip_runtime.h>
#include <hip/hip_bf16.h>

#define N_ROI 262144
#define FDIM  256
#define HDIM  64
#define NNET  128

typedef __attribute__((ext_vector_type(8))) __bf16 bf16x8;
typedef __attribute__((ext_vector_type(8))) short short8;
typedef __attribute__((ext_vector_type(4))) float floatx4;

union frag_cast { short8 s; bf16x8 b; };

// monotonic float -> uint key (order-preserving), for atomicMax segment max
__device__ __forceinline__ unsigned fkey(float f) {
  unsigned u = __float_as_uint(f);
  return (u & 0x80000000u) ? ~u : (u | 0x80000000u);
}
__device__ __forceinline__ float fkey_inv(unsigned k) {
  unsigned u = (k & 0x80000000u) ? (k ^ 0x80000000u) : ~k;
  return __uint_as_float(u);
}
__device__ __forceinline__ unsigned short f2bf(float f) {  // RNE truncate f32->bf16
  unsigned u = __float_as_uint(f);
  u += 0x7FFFu + ((u >> 16) & 1u);
  return (unsigned short)(u >> 16);
}

// -------- Kernel 1: MLP scores via bf16 MFMA + per-block segment max -------
// Block 256 thr (4 waves). Wave handles 64 ROIs x 64 hiddens:
// 4 Mtiles x 4 Ntiles of mfma_f32_16x16x32_bf16, K=256 in 8 chunks.
// A-frags straight from global (fp32->bf16 in reg); B = W1^T bf16 in LDS.
__global__ __launch_bounds__(256) void scores_mfma_kernel(
    const float* __restrict__ x, const int* __restrict__ group,
    const float* __restrict__ W1, const float* __restrict__ b1,
    const float* __restrict__ W2,
    float* __restrict__ score, unsigned* __restrict__ segmax)
{
  __shared__ unsigned short w1t[64][264];   // W1^T bf16, +8 pad -> frag reads 2-way free
  __shared__ unsigned smax[NNET];

  const int tid = threadIdx.x;
  if (tid < NNET) smax[tid] = 0u;

  // stage W1^T: 8 passes, each thread packs 8 k-consecutive bf16 -> 1 b128 write
  {
    const int n = tid & 63, kg = tid >> 6;            // kg 0..3
    for (int p = 0; p < 8; ++p) {
      const int k0 = p * 32 + kg * 8;
      unsigned short tmp[8];
#pragma unroll
      for (int j = 0; j < 8; ++j) tmp[j] = f2bf(W1[(k0 + j) * HDIM + n]);
      *(short8*)&w1t[n][k0] = *(short8*)tmp;
    }
  }
  __syncthreads();

  const int wave = tid >> 6, lane = tid & 63;
  const int col = lane & 15, quad = lane >> 4;
  const long rbase = (long)blockIdx.x * 256 + wave * 64;

  float b1v[4], w2v[4];
#pragma unroll
  for (int nt = 0; nt < 4; ++nt) { b1v[nt] = b1[nt * 16 + col]; w2v[nt] = W2[nt * 16 + col]; }

  floatx4 acc[4][4];
#pragma unroll
  for (int mt = 0; mt < 4; ++mt)
#pragma unroll
    for (int nt = 0; nt < 4; ++nt) acc[mt][nt] = (floatx4)0.f;

  for (int kc = 0; kc < 8; ++kc) {
    frag_cast bf[4];
#pragma unroll
    for (int nt = 0; nt < 4; ++nt)
      bf[nt].s = *(const short8*)&w1t[nt * 16 + col][kc * 32 + quad * 8];
#pragma unroll
    for (int mt = 0; mt < 4; ++mt) {
      const float* p = x + (rbase + mt * 16 + col) * FDIM + kc * 32 + quad * 8;
      float4 f0 = *(const float4*)p;
      float4 f1 = *(const float4*)(p + 4);
      unsigned short a8[8];
      a8[0] = f2bf(f0.x); a8[1] = f2bf(f0.y); a8[2] = f2bf(f0.z); a8[3] = f2bf(f0.w);
      a8[4] = f2bf(f1.x); a8[5] = f2bf(f1.y); a8[6] = f2bf(f1.z); a8[7] = f2bf(f1.w);
      frag_cast af; af.s = *(short8*)a8;
#pragma unroll
      for (int nt = 0; nt < 4; ++nt)
        acc[mt][nt] = __builtin_amdgcn_mfma_f32_16x16x32_bf16(af.b, bf[nt].b, acc[mt][nt], 0, 0, 0);
    }
  }

  // epilogue: +b1, relu, dot W2, reduce over 16 cols.
  // C layout: col=lane&15, row(ROI within Mtile)=quad*4+reg
#pragma unroll
  for (int mt = 0; mt < 4; ++mt) {
    float pr[4];
#pragma unroll
    for (int r = 0; r < 4; ++r) pr[r] = 0.f;
#pragma unroll
    for (int nt = 0; nt < 4; ++nt)
#pragma unroll
      for (int r = 0; r < 4; ++r)
        pr[r] += fmaxf(acc[mt][nt][r] + b1v[nt], 0.f) * w2v[nt];
#pragma unroll
    for (int off = 1; off < 16; off <<= 1)
#pragma unroll
      for (int r = 0; r < 4; ++r) pr[r] += __shfl_xor(pr[r], off, 16);
    if (col == 0) {
      const long roi = rbase + mt * 16 + quad * 4;
#pragma unroll
      for (int r = 0; r < 4; ++r) {
        score[roi + r] = pr[r];              // b2 omitted: cancels in softmax
        const int g = group[roi + r];
        atomicMax(&smax[g], fkey(pr[r]));
      }
    }
  }
  __syncthreads();
  if (tid < NNET) { unsigned k = smax[tid]; if (k) atomicMax(&segmax[tid], k); }
}

// -------- Kernel 2: w = exp(score - segmax[g]) in place, + denom -----------
__global__ __launch_bounds__(1024) void weights_kernel(
    float* __restrict__ score_w, const int* __restrict__ group,
    const unsigned* __restrict__ segmax, float* __restrict__ denom_g)
{
  __shared__ float lmax[NNET];
  __shared__ float ldenom[NNET];
  const int tid = threadIdx.x;
  if (tid < NNET) { lmax[tid] = fkey_inv(segmax[tid]); ldenom[tid] = 0.f; }
  __syncthreads();
  const long i = (long)blockIdx.x * 1024 + tid;
  const int g = group[i];
  const float w = __expf(score_w[i] - lmax[g]);
  score_w[i] = w;
  atomicAdd(&ldenom[g], w);
  __syncthreads();
  if (tid < NNET) { float v = ldenom[tid]; if (v != 0.f) atomicAdd(&denom_g[tid], v); }
}

// -------- Kernel 3: weighted segment accumulation --------------------------
// 1 block/CU (128 KiB LDS = full 128x256 accumulator -> no group filter,
// x read exactly once). Wave-per-ROI, lane-strided dims (conflict-free
// ds atomics), group/w pre-broadcast via shfl, no branches in hot loop.
__global__ __launch_bounds__(1024) void accum_kernel(
    const float* __restrict__ x, const int* __restrict__ group,
    const float* __restrict__ w, float* __restrict__ num_g)
{
  __shared__ float lnum[NNET][FDIM];   // 128 KiB
  const int tid = threadIdx.x;
  for (int i = tid; i < NNET * FDIM; i += 1024) ((float*)lnum)[i] = 0.f;
  __syncthreads();

  const int wave = tid >> 6, lane = tid & 63;
  const long i0 = (long)blockIdx.x * 1024 + wave * 64;
  const int   gv = group[i0 + lane];
  const float wv = w[i0 + lane];

#pragma unroll 4
  for (int r = 0; r < 64; ++r) {
    const int g = __shfl(gv, r, 64);
    const float wr = __shfl(wv, r, 64);
    const float* xp = x + (i0 + r) * FDIM;
    float* row = &lnum[g][0];
#pragma unroll
    for (int c = 0; c < 4; ++c)
      atomicAdd(&row[c * 64 + lane], wr * xp[c * 64 + lane]);
  }
  __syncthreads();

  for (int i = tid; i < NNET * FDIM; i += 1024)
    atomicAdd(&num_g[i], ((const float*)lnum)[i]);
}

// -------- Kernel 4: normalize ----------------------------------------------
__global__ __launch_bounds__(256) void finalize_kernel(
    const float* __restrict__ num_g, const float* __restrict__ denom_g,
    float* __restrict__ out)
{
  const int idx = blockIdx.x * 256 + threadIdx.x;   // 32768
  const int g = idx >> 8;
  const float den = denom_g[g];
  out[idx] = (den > 0.f) ? num_g[idx] / fmaxf(den, 1e-30f) : 0.f;
}

extern "C" void kernel_launch(void* const* d_in, const int* in_sizes, int n_in,
                              void* d_out, int out_size, void* d_ws, size_t ws_size,
                              hipStream_t stream)
{
  const float* x     = (const float*)d_in[0];
  const int*   group = (const int*)d_in[1];
  const float* W1    = (const float*)d_in[2];
  const float* b1    = (const float*)d_in[3];
  const float* W2    = (const float*)d_in[4];
  // d_in[5] = b2: cancels exactly in exp(score-max)/sum -> unused
  float* out = (float*)d_out;

  // workspace: score (reused in-place as w) | segmax | denom | num
  float*    score_ws  = (float*)d_ws;                  // N_ROI
  unsigned* segmax_ws = (unsigned*)(score_ws + N_ROI); // NNET
  float*    denom_ws  = (float*)(segmax_ws + NNET);    // NNET
  float*    num_ws    = denom_ws + NNET;               // NNET*FDIM

  hipMemsetAsync(segmax_ws, 0, (size_t)(NNET + NNET + NNET * FDIM) * sizeof(float), stream);

  scores_mfma_kernel<<<N_ROI / 256, 256, 0, stream>>>(x, group, W1, b1, W2, score_ws, segmax_ws);
  weights_kernel<<<N_ROI / 1024, 1024, 0, stream>>>(score_ws, group, segmax_ws, denom_ws);
  accum_kernel<<<N_ROI / 1024, 1024, 0, stream>>>(x, group, score_ws, num_ws);
  finalize_kernel<<<NNET * FDIM / 256, 256, 0, stream>>>(num_ws, denom_ws, out);

  (void)in_sizes; (void)n_in; (void)out_size; (void)ws_size;
}

// Round 3
// 525.025 us; speedup vs baseline: 1.4682x; 1.4512x over previous
//
#include <hip/hip_runtime.h>
#include <hip/hip_bf16.h>

#define N_ROI 262144
#define FDIM  256
#define HDIM  64
#define NNET  128

typedef __attribute__((ext_vector_type(8))) __bf16 bf16x8;
typedef __attribute__((ext_vector_type(8))) short short8;
typedef __attribute__((ext_vector_type(4))) short short4v;
typedef __attribute__((ext_vector_type(4))) float floatx4;

union frag_cast { short8 s; bf16x8 b; };

// monotonic float -> uint key (order-preserving), for atomicMax segment max
__device__ __forceinline__ unsigned fkey(float f) {
  unsigned u = __float_as_uint(f);
  return (u & 0x80000000u) ? ~u : (u | 0x80000000u);
}
__device__ __forceinline__ float fkey_inv(unsigned k) {
  unsigned u = (k & 0x80000000u) ? (k ^ 0x80000000u) : ~k;
  return __uint_as_float(u);
}
__device__ __forceinline__ unsigned short f2bf(float f) {  // RNE f32->bf16
  unsigned u = __float_as_uint(f);
  u += 0x7FFFu + ((u >> 16) & 1u);
  return (unsigned short)(u >> 16);
}

// -------- Kernel 1: MLP scores via bf16 MFMA + per-block segment max -------
// (unchanged from round 2 — passing; profile will rank it precisely now)
__global__ __launch_bounds__(256) void scores_mfma_kernel(
    const float* __restrict__ x, const int* __restrict__ group,
    const float* __restrict__ W1, const float* __restrict__ b1,
    const float* __restrict__ W2,
    float* __restrict__ score, unsigned* __restrict__ segmax)
{
  __shared__ unsigned short w1t[64][264];
  __shared__ unsigned smax[NNET];

  const int tid = threadIdx.x;
  if (tid < NNET) smax[tid] = 0u;

  {
    const int n = tid & 63, kg = tid >> 6;
    for (int p = 0; p < 8; ++p) {
      const int k0 = p * 32 + kg * 8;
      unsigned short tmp[8];
#pragma unroll
      for (int j = 0; j < 8; ++j) tmp[j] = f2bf(W1[(k0 + j) * HDIM + n]);
      *(short8*)&w1t[n][k0] = *(short8*)tmp;
    }
  }
  __syncthreads();

  const int wave = tid >> 6, lane = tid & 63;
  const int col = lane & 15, quad = lane >> 4;
  const long rbase = (long)blockIdx.x * 256 + wave * 64;

  float b1v[4], w2v[4];
#pragma unroll
  for (int nt = 0; nt < 4; ++nt) { b1v[nt] = b1[nt * 16 + col]; w2v[nt] = W2[nt * 16 + col]; }

  floatx4 acc[4][4];
#pragma unroll
  for (int mt = 0; mt < 4; ++mt)
#pragma unroll
    for (int nt = 0; nt < 4; ++nt) acc[mt][nt] = (floatx4)0.f;

  for (int kc = 0; kc < 8; ++kc) {
    frag_cast bf[4];
#pragma unroll
    for (int nt = 0; nt < 4; ++nt)
      bf[nt].s = *(const short8*)&w1t[nt * 16 + col][kc * 32 + quad * 8];
#pragma unroll
    for (int mt = 0; mt < 4; ++mt) {
      const float* p = x + (rbase + mt * 16 + col) * FDIM + kc * 32 + quad * 8;
      float4 f0 = *(const float4*)p;
      float4 f1 = *(const float4*)(p + 4);
      unsigned short a8[8];
      a8[0] = f2bf(f0.x); a8[1] = f2bf(f0.y); a8[2] = f2bf(f0.z); a8[3] = f2bf(f0.w);
      a8[4] = f2bf(f1.x); a8[5] = f2bf(f1.y); a8[6] = f2bf(f1.z); a8[7] = f2bf(f1.w);
      frag_cast af; af.s = *(short8*)a8;
#pragma unroll
      for (int nt = 0; nt < 4; ++nt)
        acc[mt][nt] = __builtin_amdgcn_mfma_f32_16x16x32_bf16(af.b, bf[nt].b, acc[mt][nt], 0, 0, 0);
    }
  }

#pragma unroll
  for (int mt = 0; mt < 4; ++mt) {
    float pr[4];
#pragma unroll
    for (int r = 0; r < 4; ++r) pr[r] = 0.f;
#pragma unroll
    for (int nt = 0; nt < 4; ++nt)
#pragma unroll
      for (int r = 0; r < 4; ++r)
        pr[r] += fmaxf(acc[mt][nt][r] + b1v[nt], 0.f) * w2v[nt];
#pragma unroll
    for (int off = 1; off < 16; off <<= 1)
#pragma unroll
      for (int r = 0; r < 4; ++r) pr[r] += __shfl_xor(pr[r], off, 16);
    if (col == 0) {
      const long roi = rbase + mt * 16 + quad * 4;
#pragma unroll
      for (int r = 0; r < 4; ++r) {
        score[roi + r] = pr[r];              // b2 omitted: cancels in softmax
        const int g = group[roi + r];
        atomicMax(&smax[g], fkey(pr[r]));
      }
    }
  }
  __syncthreads();
  if (tid < NNET) { unsigned k = smax[tid]; if (k) atomicMax(&segmax[tid], k); }
}

// -------- Kernel 2: weighted segment accumulation as MFMA scatter-GEMM -----
// num[g][d] = sum_k A[g][k] * x[k][d],  A[g][k] = w_k * (group_k == g).
// Block 256 thr / 4 waves, 512 ROIs per block in 16 K-chunks of 32.
// x chunk staged coalesced -> LDS bf16 (pitch 260: b-frag u16 reads 2-way max).
// A-frags built in regs from packed (g<<16|w_bf16). Denominator = extra MFMA
// with all-ones B. fp32 register accumulators; one native-atomic merge at end.
#define XPITCH 260
__global__ __launch_bounds__(256, 2) void accum_mfma_kernel(
    const float* __restrict__ x, const int* __restrict__ group,
    const float* __restrict__ score, const unsigned* __restrict__ segmax,
    float* __restrict__ num_g)   // [128][257]: d<256 num, d=256 denom
{
  __shared__ __align__(16) unsigned short xlds[32 * XPITCH];
  __shared__ unsigned gwlds[512];
  __shared__ float lmax[NNET];

  const int tid = threadIdx.x;
  if (tid < NNET) lmax[tid] = fkey_inv(segmax[tid]);
  __syncthreads();

  const long rbase = (long)blockIdx.x * 512;
  for (int rr = tid; rr < 512; rr += 256) {
    const int g = group[rbase + rr];
    const float w = __expf(score[rbase + rr] - lmax[g]);
    gwlds[rr] = ((unsigned)g << 16) | (unsigned)f2bf(w);
  }

  const int wave = tid >> 6, lane = tid & 63;
  const int col = lane & 15, quad = lane >> 4;
  const int ntb = wave * 64;                 // this wave's dim base (4 Ntiles)

  floatx4 acc[8][4];
  floatx4 accd[8];
#pragma unroll
  for (int mt = 0; mt < 8; ++mt) {
    accd[mt] = (floatx4)0.f;
#pragma unroll
    for (int nt = 0; nt < 4; ++nt) acc[mt][nt] = (floatx4)0.f;
  }

  frag_cast ones;
  {
    unsigned short o8[8];
#pragma unroll
    for (int j = 0; j < 8; ++j) o8[j] = 0x3F80;   // bf16 1.0
    ones.s = *(short8*)o8;
  }

  const float* xc = x + rbase * FDIM;
  float4 pf[8];
#pragma unroll
  for (int i = 0; i < 8; ++i) pf[i] = *(const float4*)(xc + i * 1024 + tid * 4);

  for (int c = 0; c < 16; ++c) {
    __syncthreads();   // prev chunk's reads done (c=0: gwlds/lmax staged)
#pragma unroll
    for (int i = 0; i < 8; ++i) {
      const int f = i * 1024 + tid * 4;
      const int roi = f >> 8, dim = f & 255;
      unsigned short h[4];
      h[0] = f2bf(pf[i].x); h[1] = f2bf(pf[i].y); h[2] = f2bf(pf[i].z); h[3] = f2bf(pf[i].w);
      *(short4v*)&xlds[roi * XPITCH + dim] = *(short4v*)h;
    }
    __syncthreads();
    if (c < 15) {
#pragma unroll
      for (int i = 0; i < 8; ++i)
        pf[i] = *(const float4*)(xc + (c + 1) * 8192 + i * 1024 + tid * 4);
    }

    unsigned gwv[8];
#pragma unroll
    for (int j = 0; j < 8; ++j) gwv[j] = gwlds[c * 32 + quad * 8 + j];

    frag_cast bf[4];
#pragma unroll
    for (int nt = 0; nt < 4; ++nt) {
      unsigned short bb[8];
#pragma unroll
      for (int j = 0; j < 8; ++j)
        bb[j] = xlds[(quad * 8 + j) * XPITCH + ntb + nt * 16 + col];
      bf[nt].s = *(short8*)bb;
    }

#pragma unroll
    for (int mt = 0; mt < 8; ++mt) {
      const unsigned gtarget = (unsigned)(mt * 16 + col);
      unsigned short aa[8];
#pragma unroll
      for (int j = 0; j < 8; ++j)
        aa[j] = ((gwv[j] >> 16) == gtarget) ? (unsigned short)gwv[j] : (unsigned short)0;
      frag_cast af; af.s = *(short8*)aa;
#pragma unroll
      for (int nt = 0; nt < 4; ++nt)
        acc[mt][nt] = __builtin_amdgcn_mfma_f32_16x16x32_bf16(af.b, bf[nt].b, acc[mt][nt], 0, 0, 0);
      accd[mt] = __builtin_amdgcn_mfma_f32_16x16x32_bf16(af.b, ones.b, accd[mt], 0, 0, 0);
    }
  }

  // merge: native fp32 global atomics (hardware global_atomic_add_f32)
#pragma unroll
  for (int mt = 0; mt < 8; ++mt)
#pragma unroll
    for (int nt = 0; nt < 4; ++nt)
#pragma unroll
      for (int r = 0; r < 4; ++r)
        unsafeAtomicAdd(&num_g[(mt * 16 + quad * 4 + r) * 257 + ntb + nt * 16 + col],
                        acc[mt][nt][r]);
  if (wave == 0 && col == 0) {
#pragma unroll
    for (int mt = 0; mt < 8; ++mt)
#pragma unroll
      for (int r = 0; r < 4; ++r)
        unsafeAtomicAdd(&num_g[(mt * 16 + quad * 4 + r) * 257 + 256], accd[mt][r]);
  }
}

// -------- Kernel 3: normalize ----------------------------------------------
__global__ __launch_bounds__(256) void finalize_kernel(
    const float* __restrict__ num_g, float* __restrict__ out)
{
  const int idx = blockIdx.x * 256 + threadIdx.x;   // 32768
  const int g = idx >> 8, d = idx & 255;
  const float den = num_g[g * 257 + 256];
  const float num = num_g[g * 257 + d];
  out[idx] = (den > 0.f) ? num / fmaxf(den, 1e-30f) : 0.f;
}

extern "C" void kernel_launch(void* const* d_in, const int* in_sizes, int n_in,
                              void* d_out, int out_size, void* d_ws, size_t ws_size,
                              hipStream_t stream)
{
  const float* x     = (const float*)d_in[0];
  const int*   group = (const int*)d_in[1];
  const float* W1    = (const float*)d_in[2];
  const float* b1    = (const float*)d_in[3];
  const float* W2    = (const float*)d_in[4];
  // d_in[5] = b2: cancels exactly in exp(score-max)/sum -> unused
  float* out = (float*)d_out;

  // workspace: score | segmax | num[128][257]
  float*    score_ws  = (float*)d_ws;                  // N_ROI
  unsigned* segmax_ws = (unsigned*)(score_ws + N_ROI); // NNET
  float*    num_ws    = (float*)(segmax_ws + NNET);    // NNET*257

  hipMemsetAsync(segmax_ws, 0, (size_t)(NNET + NNET * 257) * sizeof(float), stream);

  scores_mfma_kernel<<<N_ROI / 256, 256, 0, stream>>>(x, group, W1, b1, W2, score_ws, segmax_ws);
  accum_mfma_kernel<<<N_ROI / 512, 256, 0, stream>>>(x, group, score_ws, segmax_ws, num_ws);
  finalize_kernel<<<NNET * FDIM / 256, 256, 0, stream>>>(num_ws, out);

  (void)in_sizes; (void)n_in; (void)out_size; (void)ws_size;
}

// Round 4
// 517.891 us; speedup vs baseline: 1.4884x; 1.0138x over previous
//
#include <hip/hip_runtime.h>
#include <hip/hip_bf16.h>

#define N_ROI 262144
#define FDIM  256
#define HDIM  64
#define NNET  128
#define NSLICE 32

typedef __attribute__((ext_vector_type(8))) __bf16 bf16x8;
typedef __attribute__((ext_vector_type(8))) short short8;
typedef __attribute__((ext_vector_type(4))) short short4v;
typedef __attribute__((ext_vector_type(4))) float floatx4;

union frag_cast { short8 s; bf16x8 b; };

// monotonic float -> uint key (order-preserving), for atomicMax segment max
__device__ __forceinline__ unsigned fkey(float f) {
  unsigned u = __float_as_uint(f);
  return (u & 0x80000000u) ? ~u : (u | 0x80000000u);
}
__device__ __forceinline__ float fkey_inv(unsigned k) {
  unsigned u = (k & 0x80000000u) ? (k ^ 0x80000000u) : ~k;
  return __uint_as_float(u);
}
__device__ __forceinline__ unsigned short f2bf(float f) {  // RNE f32->bf16
  unsigned u = __float_as_uint(f);
  u += 0x7FFFu + ((u >> 16) & 1u);
  return (unsigned short)(u >> 16);
}

// -------- Kernel 1: MLP scores via bf16 MFMA + per-block segment max -------
// Block 256 thr / 4 waves, 256 ROIs. x staged via double-buffered LDS
// (coalesced 128B global segments -> bf16 tile, pitch 40 shorts), A-frags as
// contiguous ds_read_b128. W1^T bf16 in LDS. One barrier per K-chunk.
#define SPITCH 40
__global__ __launch_bounds__(256) void scores_mfma_kernel(
    const float* __restrict__ x, const int* __restrict__ group,
    const float* __restrict__ W1, const float* __restrict__ b1,
    const float* __restrict__ W2,
    float* __restrict__ score, unsigned* __restrict__ segmax)
{
  __shared__ unsigned short w1t[64][264];          // W1^T bf16
  __shared__ unsigned short xl[2][256 * SPITCH];   // x tile, double-buffered
  __shared__ unsigned smax[NNET];

  const int tid = threadIdx.x;
  if (tid < NNET) smax[tid] = 0u;

  // stage W1^T once
  {
    const int n = tid & 63, kg = tid >> 6;
    for (int p = 0; p < 8; ++p) {
      const int k0 = p * 32 + kg * 8;
      unsigned short tmp[8];
#pragma unroll
      for (int j = 0; j < 8; ++j) tmp[j] = f2bf(W1[(k0 + j) * HDIM + n]);
      *(short8*)&w1t[n][k0] = *(short8*)tmp;
    }
  }

  const int wave = tid >> 6, lane = tid & 63;
  const int col = lane & 15, quad = lane >> 4;
  const long rblk = (long)blockIdx.x * 256;
  const int srow = tid >> 3, sk4 = tid & 7;        // this thread's 8 staging slots
  // thread stages rows srow, srow+32, ..., srow+224 at k-quad sk4

  float b1v[4], w2v[4];
#pragma unroll
  for (int nt = 0; nt < 4; ++nt) { b1v[nt] = b1[nt * 16 + col]; w2v[nt] = W2[nt * 16 + col]; }

  floatx4 acc[4][4];
#pragma unroll
  for (int mt = 0; mt < 4; ++mt)
#pragma unroll
    for (int nt = 0; nt < 4; ++nt) acc[mt][nt] = (floatx4)0.f;

  // prefetch + stage chunk 0
  float4 pf[8];
#pragma unroll
  for (int i = 0; i < 8; ++i)
    pf[i] = *(const float4*)(x + (rblk + srow + i * 32) * FDIM + sk4 * 4);
#pragma unroll
  for (int i = 0; i < 8; ++i) {
    unsigned short h[4];
    h[0] = f2bf(pf[i].x); h[1] = f2bf(pf[i].y); h[2] = f2bf(pf[i].z); h[3] = f2bf(pf[i].w);
    *(short4v*)&xl[0][(srow + i * 32) * SPITCH + sk4 * 4] = *(short4v*)h;
  }
  __syncthreads();

  for (int c = 0; c < 8; ++c) {
    if (c < 7) {   // issue next chunk's loads now; land during compute
#pragma unroll
      for (int i = 0; i < 8; ++i)
        pf[i] = *(const float4*)(x + (rblk + srow + i * 32) * FDIM + (c + 1) * 32 + sk4 * 4);
    }
    const unsigned short* xb = &xl[c & 1][0];
    frag_cast bf[4];
#pragma unroll
    for (int nt = 0; nt < 4; ++nt)
      bf[nt].s = *(const short8*)&w1t[nt * 16 + col][c * 32 + quad * 8];
#pragma unroll
    for (int mt = 0; mt < 4; ++mt) {
      frag_cast af;
      af.s = *(const short8*)&xb[(wave * 64 + mt * 16 + col) * SPITCH + quad * 8];
#pragma unroll
      for (int nt = 0; nt < 4; ++nt)
        acc[mt][nt] = __builtin_amdgcn_mfma_f32_16x16x32_bf16(af.b, bf[nt].b, acc[mt][nt], 0, 0, 0);
    }
    if (c < 7) {
#pragma unroll
      for (int i = 0; i < 8; ++i) {
        unsigned short h[4];
        h[0] = f2bf(pf[i].x); h[1] = f2bf(pf[i].y); h[2] = f2bf(pf[i].z); h[3] = f2bf(pf[i].w);
        *(short4v*)&xl[(c + 1) & 1][(srow + i * 32) * SPITCH + sk4 * 4] = *(short4v*)h;
      }
      __syncthreads();
    }
  }

  // epilogue: +b1, relu, dot W2, reduce over 16 cols. C row = quad*4+reg.
#pragma unroll
  for (int mt = 0; mt < 4; ++mt) {
    float pr[4];
#pragma unroll
    for (int r = 0; r < 4; ++r) pr[r] = 0.f;
#pragma unroll
    for (int nt = 0; nt < 4; ++nt)
#pragma unroll
      for (int r = 0; r < 4; ++r)
        pr[r] += fmaxf(acc[mt][nt][r] + b1v[nt], 0.f) * w2v[nt];
#pragma unroll
    for (int off = 1; off < 16; off <<= 1)
#pragma unroll
      for (int r = 0; r < 4; ++r) pr[r] += __shfl_xor(pr[r], off, 16);
    if (col == 0) {
      const long roi = rblk + wave * 64 + mt * 16 + quad * 4;
#pragma unroll
      for (int r = 0; r < 4; ++r) {
        score[roi + r] = pr[r];              // b2 omitted: cancels in softmax
        const int g = group[roi + r];
        atomicMax(&smax[g], fkey(pr[r]));
      }
    }
  }
  __syncthreads();
  if (tid < NNET) { unsigned k = smax[tid]; if (k) atomicMax(&segmax[tid], k); }
}

// -------- Kernel 2: weighted segment accumulation as MFMA scatter-GEMM -----
// num[g][d] = sum_k A[g][k]*x[k][d], A[g][k] = w_k * (group_k==g).
// 512 ROIs/block in 16 chunks of 32; double-buffered LDS; register acc;
// merge via native fp32 atomics into one of NSLICE replica slices.
#define XPITCH 260
__global__ __launch_bounds__(256, 2) void accum_mfma_kernel(
    const float* __restrict__ x, const int* __restrict__ group,
    const float* __restrict__ score, const unsigned* __restrict__ segmax,
    float* __restrict__ num_g)   // [NSLICE][128][257]: d<256 num, d=256 denom
{
  __shared__ __align__(16) unsigned short xlds[2][32 * XPITCH];
  __shared__ unsigned gwlds[512];
  __shared__ float lmax[NNET];

  const int tid = threadIdx.x;
  if (tid < NNET) lmax[tid] = fkey_inv(segmax[tid]);
  __syncthreads();

  const long rbase = (long)blockIdx.x * 512;
  for (int rr = tid; rr < 512; rr += 256) {
    const int g = group[rbase + rr];
    const float w = __expf(score[rbase + rr] - lmax[g]);
    gwlds[rr] = ((unsigned)g << 16) | (unsigned)f2bf(w);
  }

  const int wave = tid >> 6, lane = tid & 63;
  const int col = lane & 15, quad = lane >> 4;
  const int ntb = wave * 64;

  floatx4 acc[8][4];
  floatx4 accd[8];
#pragma unroll
  for (int mt = 0; mt < 8; ++mt) {
    accd[mt] = (floatx4)0.f;
#pragma unroll
    for (int nt = 0; nt < 4; ++nt) acc[mt][nt] = (floatx4)0.f;
  }

  frag_cast ones;
  {
    unsigned short o8[8];
#pragma unroll
    for (int j = 0; j < 8; ++j) o8[j] = 0x3F80;   // bf16 1.0
    ones.s = *(short8*)o8;
  }

  const float* xc = x + rbase * FDIM;
  float4 pf[8];
#pragma unroll
  for (int i = 0; i < 8; ++i) pf[i] = *(const float4*)(xc + i * 1024 + tid * 4);
#pragma unroll
  for (int i = 0; i < 8; ++i) {   // stage chunk 0
    const int f = i * 1024 + tid * 4;
    const int roi = f >> 8, dim = f & 255;
    unsigned short h[4];
    h[0] = f2bf(pf[i].x); h[1] = f2bf(pf[i].y); h[2] = f2bf(pf[i].z); h[3] = f2bf(pf[i].w);
    *(short4v*)&xlds[0][roi * XPITCH + dim] = *(short4v*)h;
  }
  __syncthreads();

  for (int c = 0; c < 16; ++c) {
    if (c < 15) {   // issue next chunk's loads now
#pragma unroll
      for (int i = 0; i < 8; ++i)
        pf[i] = *(const float4*)(xc + (c + 1) * 8192 + i * 1024 + tid * 4);
    }

    unsigned gwv[8];
#pragma unroll
    for (int j = 0; j < 8; ++j) gwv[j] = gwlds[c * 32 + quad * 8 + j];

    const unsigned short* xb = &xlds[c & 1][0];
    frag_cast bf[4];
#pragma unroll
    for (int nt = 0; nt < 4; ++nt) {
      unsigned short bb[8];
#pragma unroll
      for (int j = 0; j < 8; ++j)
        bb[j] = xb[(quad * 8 + j) * XPITCH + ntb + nt * 16 + col];
      bf[nt].s = *(short8*)bb;
    }

#pragma unroll
    for (int mt = 0; mt < 8; ++mt) {
      const unsigned gtarget = (unsigned)(mt * 16 + col);
      unsigned short aa[8];
#pragma unroll
      for (int j = 0; j < 8; ++j)
        aa[j] = ((gwv[j] >> 16) == gtarget) ? (unsigned short)gwv[j] : (unsigned short)0;
      frag_cast af; af.s = *(short8*)aa;
#pragma unroll
      for (int nt = 0; nt < 4; ++nt)
        acc[mt][nt] = __builtin_amdgcn_mfma_f32_16x16x32_bf16(af.b, bf[nt].b, acc[mt][nt], 0, 0, 0);
      accd[mt] = __builtin_amdgcn_mfma_f32_16x16x32_bf16(af.b, ones.b, accd[mt], 0, 0, 0);
    }

    if (c < 15) {
#pragma unroll
      for (int i = 0; i < 8; ++i) {
        const int f = i * 1024 + tid * 4;
        const int roi = f >> 8, dim = f & 255;
        unsigned short h[4];
        h[0] = f2bf(pf[i].x); h[1] = f2bf(pf[i].y); h[2] = f2bf(pf[i].z); h[3] = f2bf(pf[i].w);
        *(short4v*)&xlds[(c + 1) & 1][roi * XPITCH + dim] = *(short4v*)h;
      }
      __syncthreads();
    }
  }

  // merge into replica slice (spreads atomic contention NSLICE-fold)
  float* slice = num_g + (size_t)(blockIdx.x & (NSLICE - 1)) * (NNET * 257);
#pragma unroll
  for (int mt = 0; mt < 8; ++mt)
#pragma unroll
    for (int nt = 0; nt < 4; ++nt)
#pragma unroll
      for (int r = 0; r < 4; ++r)
        unsafeAtomicAdd(&slice[(mt * 16 + quad * 4 + r) * 257 + ntb + nt * 16 + col],
                        acc[mt][nt][r]);
  if (wave == 0 && col == 0) {
#pragma unroll
    for (int mt = 0; mt < 8; ++mt)
#pragma unroll
      for (int r = 0; r < 4; ++r)
        unsafeAtomicAdd(&slice[(mt * 16 + quad * 4 + r) * 257 + 256], accd[mt][r]);
  }
}

// -------- Kernel 3: sum slices + normalize ---------------------------------
__global__ __launch_bounds__(256) void finalize_kernel(
    const float* __restrict__ num_g, float* __restrict__ out)
{
  const int idx = blockIdx.x * 256 + threadIdx.x;   // 32768
  const int g = idx >> 8, d = idx & 255;
  float num = 0.f, den = 0.f;
#pragma unroll
  for (int s = 0; s < NSLICE; ++s) {
    num += num_g[(size_t)s * (NNET * 257) + g * 257 + d];
    den += num_g[(size_t)s * (NNET * 257) + g * 257 + 256];
  }
  out[idx] = (den > 0.f) ? num / fmaxf(den, 1e-30f) : 0.f;
}

extern "C" void kernel_launch(void* const* d_in, const int* in_sizes, int n_in,
                              void* d_out, int out_size, void* d_ws, size_t ws_size,
                              hipStream_t stream)
{
  const float* x     = (const float*)d_in[0];
  const int*   group = (const int*)d_in[1];
  const float* W1    = (const float*)d_in[2];
  const float* b1    = (const float*)d_in[3];
  const float* W2    = (const float*)d_in[4];
  // d_in[5] = b2: cancels exactly in exp(score-max)/sum -> unused
  float* out = (float*)d_out;

  // workspace: score | segmax | num[NSLICE][128][257]
  float*    score_ws  = (float*)d_ws;                  // N_ROI
  unsigned* segmax_ws = (unsigned*)(score_ws + N_ROI); // NNET
  float*    num_ws    = (float*)(segmax_ws + NNET);    // NSLICE*NNET*257

  hipMemsetAsync(segmax_ws, 0,
                 (size_t)(NNET + (size_t)NSLICE * NNET * 257) * sizeof(float), stream);

  scores_mfma_kernel<<<N_ROI / 256, 256, 0, stream>>>(x, group, W1, b1, W2, score_ws, segmax_ws);
  accum_mfma_kernel<<<N_ROI / 512, 256, 0, stream>>>(x, group, score_ws, segmax_ws, num_ws);
  finalize_kernel<<<NNET * FDIM / 256, 256, 0, stream>>>(num_ws, out);

  (void)in_sizes; (void)n_in; (void)out_size; (void)ws_size;
}